// Round 4
// baseline (736.778 us; speedup 1.0000x reference)
//
#include <hip/hip_runtime.h>
#include <hip/hip_bf16.h>

#define S_LEN 1024
#define BATCH 2048
#define HID   64
#define MB    4               // batch rows per block = waves per block
#define NBLK  (BATCH / MB)    // 512 blocks -> 2 per CU, 8 waves/CU (2/SIMD)
#define NTHR  256             // 4 waves

typedef _Float16 half8 __attribute__((ext_vector_type(8)));
typedef float    f32x4 __attribute__((ext_vector_type(4)));

#define L2E 1.4426950408889634f

// R15: BARRIER-FREE wave-per-row structure.
// Evidence trail: R13 (rcp fusion cut VALU 10%, time flat) -> not issue-bound.
// R14 (1 block/CU, VALUBusy fell to 42%) -> TLP load-bearing; fixed cost must
// be DELETED, not amortized. Here each wave owns one batch row: all 256 gate
// units computed in-wave (32 MFMAs, M-replication of the single row), unit
// selected per-lane via cndmask (u = lane, val = acc[ct=quad][0]), h exchanged
// through a wave-private 128B LDS buffer -> same-wave write->read needs only
// lgkmcnt, NO s_barrier in the recurrence. 2048 independent waves, 2/SIMD.
// Cost: 4x MFMA issue (~310 cyc/SIMD-step, was idle pipe anyway).
// Kept: NO setprio (m190 lockstep null), NO variable C-in fold (R13: +13%
// VALU from rematerialization), rcp fusion (R13), persistent zero4 C-in.
__global__ __launch_bounds__(NTHR, 2) void lstm_kernel(
    const float* __restrict__ x,      // (S, BATCH)
    const float* __restrict__ W_ih,   // (256,1)
    const float* __restrict__ W_hh,   // (256,64)
    const float* __restrict__ b_ih,   // (256,)
    const float* __restrict__ b_hh,   // (256,)
    const float* __restrict__ fc1_w,  // (128,64)
    const float* __restrict__ fc1_b,  // (128,)
    const float* __restrict__ fc2_w,  // (5,128)
    const float* __restrict__ fc2_b,  // (5,)
    float* __restrict__ out)          // (BATCH,5)
{
    // x staged ONCE in [s][b] layout (R14's [b][s] transpose caused 2.25M
    // conflict cycles; reverted). In-loop x read is a wave-uniform broadcast.
    __shared__ __align__(16) float    xs[S_LEN * MB];                // 16 KB
    __shared__ __align__(16) _Float16 h_lds[MB][HID];                // 512 B
    __shared__ __align__(16) float    head_lds[MB * HID + MB * 128]; // 3 KB

    const int tid  = threadIdx.x;
    const int lane = tid & 63;
    const int wr   = tid >> 6;        // wave index = batch row within block
    const int l15  = lane & 15;
    const int quad = lane >> 4;       // 0..3
    const int b0   = blockIdx.x * MB;

    // ---- stage x: 1024 rows of float4 (x[s][b0..b0+3]), 4 rows/thread ----
    {
        float4* xs4 = (float4*)xs;
        #pragma unroll
        for (int t = 0; t < 4; ++t) {
            const int s = tid + 256 * t;
            xs4[s] = *(const float4*)(x + (size_t)s * BATCH + b0);
        }
    }

    // ---- zero h buffers (h0 = 0): 256 halfs = 128 dwords ----
    if (tid < MB * HID / 2) ((unsigned*)h_lds)[tid] = 0u;

    // ---- stationary W_hh B-fragments: FULL weight set per wave (128 VGPR) --
    // (g,ct,kt): frag col n = g*64 + ct*16 + l15, k = quad*8 + kt*32 + j.
    // Pre-scaled by -log2e (sigmoid) / -2log2e (tanh on g gate).
    half8 wfrag[4][4][2];
    #pragma unroll
    for (int g = 0; g < 4; ++g) {
        const float sc = (g == 2) ? (-2.0f * L2E) : (-L2E);
        #pragma unroll
        for (int ct = 0; ct < 4; ++ct) {
            const float* wrow = W_hh + (g * 64 + ct * 16 + l15) * HID + quad * 8;
            #pragma unroll
            for (int kt = 0; kt < 2; ++kt) {
                const float4 v0 = *(const float4*)(wrow + kt * 32);
                const float4 v1 = *(const float4*)(wrow + kt * 32 + 4);
                half8 f;
                f[0] = (_Float16)(v0.x * sc); f[1] = (_Float16)(v0.y * sc);
                f[2] = (_Float16)(v0.z * sc); f[3] = (_Float16)(v0.w * sc);
                f[4] = (_Float16)(v1.x * sc); f[5] = (_Float16)(v1.y * sc);
                f[6] = (_Float16)(v1.z * sc); f[7] = (_Float16)(v1.w * sc);
                wfrag[g][ct][kt] = f;
            }
        }
    }

    // ---- elementwise ownership: lane owns unit u = lane of row wr ----
    const int u = lane;
    float wih_s[4], bias_s[4];
    #pragma unroll
    for (int g = 0; g < 4; ++g) {
        const int n = g * 64 + u;
        const float sc = (g == 2) ? (-2.0f * L2E) : (-L2E);
        wih_s[g]  = W_ih[n] * sc;
        bias_s[g] = (b_ih[n] + b_hh[n]) * sc;
    }

    float c = 0.0f;
    const f32x4 zero4 = {0.f, 0.f, 0.f, 0.f};   // persistent C-operand regs

    // wave-private h buffer pointers
    const _Float16* arp = &h_lds[wr][0] + quad * 8;  // A-frag: h[8q..8q+7] (+32)
    _Float16*       hwp = &h_lds[wr][0] + lane;      // own unit write
    const float*    xp  = xs + wr;                   // step s value at xp[4*s]

    // unit-select predicates (uniform per 16-lane cluster; hoisted v_cmp)
    const bool q0  = (quad == 0);
    const bool q2  = (quad == 2);
    const bool qlo = (quad < 2);

    __syncthreads();   // x staged + h zeroed visible (waves drift freely after)

    #pragma unroll 1
    for (int s = 0; s < S_LEN; ++s) {
        // same-wave LDS: compiler orders write(s-1) -> read(s) via lgkmcnt
        half8 a0 = *(const half8*)(arp);          // k 0..31 (16-lane broadcast)
        half8 a1 = *(const half8*)(arp + 32);     // k 32..63
        const float xv = xp[4 * s];               // wave-uniform broadcast

        float gate[4];
        #pragma unroll
        for (int g = 0; g < 4; ++g) {
            // 4 independent 2-deep MFMA chains (col-tiles), then unit select
            f32x4 acc0 = __builtin_amdgcn_mfma_f32_16x16x32_f16(a0, wfrag[g][0][0], zero4, 0, 0, 0);
            f32x4 acc1 = __builtin_amdgcn_mfma_f32_16x16x32_f16(a0, wfrag[g][1][0], zero4, 0, 0, 0);
            f32x4 acc2 = __builtin_amdgcn_mfma_f32_16x16x32_f16(a0, wfrag[g][2][0], zero4, 0, 0, 0);
            f32x4 acc3 = __builtin_amdgcn_mfma_f32_16x16x32_f16(a0, wfrag[g][3][0], zero4, 0, 0, 0);
            acc0 = __builtin_amdgcn_mfma_f32_16x16x32_f16(a1, wfrag[g][0][1], acc0, 0, 0, 0);
            acc1 = __builtin_amdgcn_mfma_f32_16x16x32_f16(a1, wfrag[g][1][1], acc1, 0, 0, 0);
            acc2 = __builtin_amdgcn_mfma_f32_16x16x32_f16(a1, wfrag[g][2][1], acc2, 0, 0, 0);
            acc3 = __builtin_amdgcn_mfma_f32_16x16x32_f16(a1, wfrag[g][3][1], acc3, 0, 0, 0);
            // C[row][col=l15] identical over rows; lane's unit = 16*quad+l15
            // -> pick col-tile ct == quad via 3 cndmasks
            const float v01 = q0 ? acc0[0] : acc1[0];
            const float v23 = q2 ? acc2[0] : acc3[0];
            gate[g] = (qlo ? v01 : v23) + __builtin_fmaf(xv, wih_s[g], bias_s[g]);
        }

        // ---- elementwise (R13 rcp-fused): 5 exp2 + 3 rcp ----
        const float eA = __builtin_amdgcn_exp2f(gate[0]);
        const float eF = __builtin_amdgcn_exp2f(gate[1]);
        const float eC = __builtin_amdgcn_exp2f(gate[2]);
        const float eO = __builtin_amdgcn_exp2f(gate[3]);

        const float f_ = __builtin_amdgcn_rcpf(1.0f + eF);
        const float R1 = __builtin_amdgcn_rcpf((1.0f + eA) * (1.0f + eC));
        const float ig = __builtin_fmaf(-eC, R1, R1);

        c = __builtin_fmaf(f_, c, ig);

        const float eT = __builtin_amdgcn_exp2f((-2.0f * L2E) * c);
        const float R2 = __builtin_amdgcn_rcpf((1.0f + eO) * (1.0f + eT));
        const float h  = __builtin_fmaf(-eT, R2, R2);

        hwp[0] = (_Float16)h;      // own unit; next iter's read waits lgkmcnt
        // NO s_barrier: wave-private buffer, waves fully independent
    }

    // ---------- fused FC head on final cell states (no activation) ----------
    float* c_lds  = head_lds;             // MB*64 floats: [b][u]
    float* h1_lds = head_lds + MB * HID;  // MB*128 floats: [b][j]
    c_lds[wr * HID + u] = c;
    __syncthreads();

    for (int idx = tid; idx < MB * 128; idx += NTHR) {
        const int b = idx >> 7, j = idx & 127;
        const float* wrow = fc1_w + j * HID;
        const float* crow = c_lds + b * HID;
        float acc = fc1_b[j];
        #pragma unroll
        for (int k = 0; k < HID; k += 4)
            acc += crow[k] * wrow[k] + crow[k+1] * wrow[k+1]
                 + crow[k+2] * wrow[k+2] + crow[k+3] * wrow[k+3];
        h1_lds[idx] = acc;
    }
    __syncthreads();

    if (tid < MB * 5) {
        const int b = tid / 5, q = tid % 5;
        const float* wrow = fc2_w + q * 128;
        const float* hrow = h1_lds + b * 128;
        float acc = fc2_b[q];
        #pragma unroll 4
        for (int j = 0; j < 128; ++j) acc += hrow[j] * wrow[j];
        out[(b0 + b) * 5 + q] = acc;
    }
}

extern "C" void kernel_launch(void* const* d_in, const int* in_sizes, int n_in,
                              void* d_out, int out_size, void* d_ws, size_t ws_size,
                              hipStream_t stream) {
    const float* x     = (const float*)d_in[0];
    const float* W_ih  = (const float*)d_in[1];
    const float* W_hh  = (const float*)d_in[2];
    const float* b_ih  = (const float*)d_in[3];
    const float* b_hh  = (const float*)d_in[4];
    const float* fc1_w = (const float*)d_in[5];
    const float* fc1_b = (const float*)d_in[6];
    const float* fc2_w = (const float*)d_in[7];
    const float* fc2_b = (const float*)d_in[8];
    float* out = (float*)d_out;

    lstm_kernel<<<NBLK, NTHR, 0, stream>>>(x, W_ih, W_hh, b_ih, b_hh,
                                           fc1_w, fc1_b, fc2_w, fc2_b, out);
}

// Round 5
// 517.634 us; speedup vs baseline: 1.4234x; 1.4234x over previous
//
#include <hip/hip_runtime.h>
#include <hip/hip_bf16.h>

#define S_LEN 1024
#define BATCH 2048
#define HID   64
#define MB    8               // rows per block = 2 independent groups of 4
#define NBLK  (BATCH / MB)    // 256 blocks -> 1 per CU
#define NTHR  512             // 8 waves = 2 per SIMD (one A + one B per SIMD)

typedef _Float16 half8 __attribute__((ext_vector_type(8)));
typedef float    f32x4 __attribute__((ext_vector_type(4)));

#define L2E 1.4426950408889634f
#define HSTRIDE 80            // 160 B rows: A-frag b128 reads land 2-way/free

// R16: STATIC ANTIPHASE role-split.
// Evidence: R2 counters show VALUBusy(54)+MfmaUtil(40) ~= 94% with step==
// VALU+MFMA issue-sum (700 of 735 cyc) -> pipes run IN SERIES (waves convoy
// into the same phase). Floor if overlapped = max(390,310)+sync ~= 460 cyc.
// Structure: 1 block/CU, 8 waves, two independent 4-row groups; schedule
// alternates {A:EW | B:MFMA} barrier {A:MFMA | B:EW} barrier. Wave i lands on
// SIMD i%4 -> every SIMD hosts one A-wave + one B-wave -> VALU and MFMA pipes
// loaded simultaneously by different waves. Each group is the proven R2
// kernel (8 MFMAs/wave-step, HSTRIDE=80); phase discipline makes a SINGLE
// h-buffer per group legal (write and read separated by a barrier).
// Calibration fix (R4): 16x16x32 MFMA costs ~19.4 cyc/SIMD, not 4.85 (that
// was per-CU) -> never replicate M beyond 4x.
// Kept: NO setprio (m190), NO variable C-in fold (R13: rematerialization),
// rcp fusion (R13) extended with paired-rcp (8 -> 7 trans).
__global__ __launch_bounds__(NTHR, 2) void lstm_kernel(
    const float* __restrict__ x,      // (S, BATCH)
    const float* __restrict__ W_ih,   // (256,1)
    const float* __restrict__ W_hh,   // (256,64)
    const float* __restrict__ b_ih,   // (256,)
    const float* __restrict__ b_hh,   // (256,)
    const float* __restrict__ fc1_w,  // (128,64)
    const float* __restrict__ fc1_b,  // (128,)
    const float* __restrict__ fc2_w,  // (5,128)
    const float* __restrict__ fc2_b,  // (5,)
    float* __restrict__ out)          // (BATCH,5)
{
    __shared__ __align__(16) float    xs[S_LEN * MB];                // 32 KB [s][8]
    __shared__ __align__(16) _Float16 h_lds[2][4 * HSTRIDE];         // 1280 B
    __shared__ __align__(16) float    head_lds[MB * HID + MB * 128]; // 6 KB

    const int tid  = threadIdx.x;
    const int lane = tid & 63;
    const int wave = tid >> 6;        // 0..7; SIMD = wave & 3
    const int l15  = lane & 15;
    const int quad = lane >> 4;       // 0..3
    const int b0   = blockIdx.x * MB;

    const bool gA  = (wave < 4);      // group A: waves 0-3; B: 4-7
    const int  wg  = wave & 3;        // wave-in-group: unit slice index
    const int  rowl = (gA ? quad : 4 + quad);   // local batch row 0..7

    // ---- stage x: (S,8) slice as float4 pairs, 4 per thread ----
    {
        float4* xs4 = (float4*)xs;
        #pragma unroll
        for (int t = 0; t < 4; ++t) {
            const int idx = tid + 512 * t;              // 0..2047
            const int s = idx >> 1, hh = (idx & 1) * 4;
            xs4[idx] = *(const float4*)(x + (size_t)s * BATCH + b0 + hh);
        }
    }

    // ---- zero both groups' h buffers (h0 = 0): 640 halves = 320 dwords ----
    if (tid < 320) ((unsigned*)h_lds)[tid] = 0u;

    // ---- stationary W_hh B-fragments, per-wave unit slice (32 VGPRs) ----
    // wave w, gate g: frag col n=l15 <-> W_hh row g*64 + 16*wg + l15.
    // Pre-scaled by -log2e (sigmoid) / -2log2e (tanh on g gate).
    half8 wfrag[4][2];
    #pragma unroll
    for (int g = 0; g < 4; ++g) {
        const float sc = (g == 2) ? (-2.0f * L2E) : (-L2E);
        const float* wr = W_hh + (g * 64 + 16 * wg + l15) * HID + quad * 8;
        #pragma unroll
        for (int kt = 0; kt < 2; ++kt) {
            half8 f;
            #pragma unroll
            for (int j = 0; j < 8; ++j) f[j] = (_Float16)(wr[kt * 32 + j] * sc);
            wfrag[g][kt] = f;
        }
    }

    // ---- elementwise ownership: thread -> (row = rowl, unit u = 16wg+l15) --
    const int u = 16 * wg + l15;
    float wih_s[4], bias_s[4];
    #pragma unroll
    for (int g = 0; g < 4; ++g) {
        const int n = g * 64 + u;
        const float sc = (g == 2) ? (-2.0f * L2E) : (-L2E);
        wih_s[g]  = W_ih[n] * sc;
        bias_s[g] = (b_ih[n] + b_hh[n]) * sc;
    }

    float c = 0.0f;
    const f32x4 zero4 = {0.f, 0.f, 0.f, 0.f};   // persistent C-operand regs

    // group-dependent pointers (single h buffer per group: phase-separated)
    _Float16* hbase = &h_lds[gA ? 0 : 1][0];
    const _Float16* arp = hbase + (l15 >> 2) * HSTRIDE + quad * 8;  // A-frag
    _Float16*       hwp = hbase + quad * HSTRIDE + u;               // h write
    const float*    xp  = xs + rowl;            // step s value at xp[8*s]

    f32x4 acc[4];
    #pragma unroll
    for (int g = 0; g < 4; ++g) acc[g] = zero4;  // A's MFMA(0) on h0=0 == 0

    auto do_mfma = [&]() {
        half8 a0 = *(const half8*)(arp);          // k 0..31
        half8 a1 = *(const half8*)(arp + 32);     // k 32..63
        #pragma unroll
        for (int g = 0; g < 4; ++g) {
            acc[g] = __builtin_amdgcn_mfma_f32_16x16x32_f16(a0, wfrag[g][0], zero4, 0, 0, 0);
            acc[g] = __builtin_amdgcn_mfma_f32_16x16x32_f16(a1, wfrag[g][1], acc[g], 0, 0, 0);
        }
    };

    auto do_ew = [&](int s) {
        const float xv = xp[8 * s];               // 16-lane ds broadcast
        const float gi = acc[0][0] + __builtin_fmaf(xv, wih_s[0], bias_s[0]);
        const float gf = acc[1][0] + __builtin_fmaf(xv, wih_s[1], bias_s[1]);
        const float gg = acc[2][0] + __builtin_fmaf(xv, wih_s[2], bias_s[2]);
        const float go = acc[3][0] + __builtin_fmaf(xv, wih_s[3], bias_s[3]);

        const float eA = __builtin_amdgcn_exp2f(gi);   // e^-ri
        const float eF = __builtin_amdgcn_exp2f(gf);   // e^-rf
        const float eC = __builtin_amdgcn_exp2f(gg);   // e^-2rg
        const float eO = __builtin_amdgcn_exp2f(go);   // e^-ro

        // paired rcp: r = 1/(P*Q) gives f_=r*Q=1/P and R1=r*P=1/Q (7 trans)
        const float P  = 1.0f + eF;
        const float Q  = (1.0f + eA) * (1.0f + eC);
        const float r  = __builtin_amdgcn_rcpf(P * Q);
        const float f_ = r * Q;
        const float R1 = r * P;
        const float ig = __builtin_fmaf(-eC, R1, R1);  // (1-eC)/Q

        c = __builtin_fmaf(f_, c, ig);

        const float eT = __builtin_amdgcn_exp2f((-2.0f * L2E) * c);
        const float R2 = __builtin_amdgcn_rcpf((1.0f + eO) * (1.0f + eT));
        const float h  = __builtin_fmaf(-eT, R2, R2);

        hwp[0] = (_Float16)h;
    };

    __syncthreads();   // x staged + h zeroed visible

    #pragma unroll 1
    for (int s = 0; s < S_LEN; ++s) {
        // phase1: A elementwise(s) on acc from its previous MFMA;
        //         B computes MFMA(s) from h_B(s-1)
        if (gA) do_ew(s); else do_mfma();
        __syncthreads();
        // phase2: A computes MFMA(s+1) from h_A(s); B elementwise(s)
        if (gA) { if (s + 1 < S_LEN) do_mfma(); } else do_ew(s);
        __syncthreads();
    }

    // ---------- fused FC head on final cell states (no activation) ----------
    float* c_lds  = head_lds;             // MB*64 floats: [b][u]
    float* h1_lds = head_lds + MB * HID;  // MB*128 floats: [b][j]
    c_lds[rowl * HID + u] = c;
    __syncthreads();

    for (int idx = tid; idx < MB * 128; idx += NTHR) {
        const int b = idx >> 7, j = idx & 127;
        const float* wrow = fc1_w + j * HID;
        const float* crow = c_lds + b * HID;
        float acc2 = fc1_b[j];
        #pragma unroll
        for (int k = 0; k < HID; k += 4)
            acc2 += crow[k] * wrow[k] + crow[k+1] * wrow[k+1]
                  + crow[k+2] * wrow[k+2] + crow[k+3] * wrow[k+3];
        h1_lds[idx] = acc2;
    }
    __syncthreads();

    if (tid < MB * 5) {
        const int b = tid / 5, q = tid % 5;
        const float* wrow = fc2_w + q * 128;
        const float* hrow = h1_lds + b * 128;
        float acc2 = fc2_b[q];
        #pragma unroll 4
        for (int j = 0; j < 128; ++j) acc2 += hrow[j] * wrow[j];
        out[(b0 + b) * 5 + q] = acc2;
    }
}

extern "C" void kernel_launch(void* const* d_in, const int* in_sizes, int n_in,
                              void* d_out, int out_size, void* d_ws, size_t ws_size,
                              hipStream_t stream) {
    const float* x     = (const float*)d_in[0];
    const float* W_ih  = (const float*)d_in[1];
    const float* W_hh  = (const float*)d_in[2];
    const float* b_ih  = (const float*)d_in[3];
    const float* b_hh  = (const float*)d_in[4];
    const float* fc1_w = (const float*)d_in[5];
    const float* fc1_b = (const float*)d_in[6];
    const float* fc2_w = (const float*)d_in[7];
    const float* fc2_b = (const float*)d_in[8];
    float* out = (float*)d_out;

    lstm_kernel<<<NBLK, NTHR, 0, stream>>>(x, W_ih, W_hh, b_ih, b_hh,
                                           fc1_w, fc1_b, fc2_w, fc2_b, out);
}

// Round 6
// 355.670 us; speedup vs baseline: 2.0715x; 1.4554x over previous
//
#include <hip/hip_runtime.h>
#include <hip/hip_bf16.h>

#define S_LEN 1024
#define BATCH 2048
#define HID   64
#define MB    4               // batch rows per block
#define NBLK  (BATCH / MB)    // 512 blocks -> 2 per CU (measured optimum)
#define NTHR  (MB * HID)      // 256 threads = 4 waves

typedef _Float16 half8 __attribute__((ext_vector_type(8)));
typedef float    f32x4 __attribute__((ext_vector_type(4)));

#define L2E 1.4426950408889634f
#define HSTRIDE 80            // 160 B rows: A-frag b128 reads land 2-way/free

// R17: CHAIN-SHORTENING on the proven R2 skeleton (313 us).
// Landscape mapped R3/R4/R5: every block/barrier restructure loses
// (407/777/503 us). R2 model: chain-latency-bound, per-step chain ~=
// ds_read(130) + 2-deep MFMA(180) + EW(120) + write(60) ~= 490 cyc, 53%
// cross-block overlap -> 735 cyc/step. This round cuts the chain:
//  (1) independent MFMA halves (accA,accB) + post-add: 2-deep MFMA dep
//      chain -> 1-deep (saves ~30-40 cyc on path, +4 v_add off-path)
//  (2) gpre[g] = xv*wih+bias precomputed for s+1 in the write->barrier
//      shadow: gate fma + x ds_read leave the critical path
//  (3) paired-rcp EW kept (7 trans, R5-verified numerics)
// Kept invariants: 2 blk/CU, 4 waves, 1 barrier/step, HSTRIDE=80, NO setprio
// (m190 lockstep null), NO f32x4 C-in fold (R1: +13% VALU rematerialization).
__global__ __launch_bounds__(NTHR, 2) void lstm_kernel(
    const float* __restrict__ x,      // (S, BATCH)
    const float* __restrict__ W_ih,   // (256,1)
    const float* __restrict__ W_hh,   // (256,64)
    const float* __restrict__ b_ih,   // (256,)
    const float* __restrict__ b_hh,   // (256,)
    const float* __restrict__ fc1_w,  // (128,64)
    const float* __restrict__ fc1_b,  // (128,)
    const float* __restrict__ fc2_w,  // (5,128)
    const float* __restrict__ fc2_b,  // (5,)
    float* __restrict__ out)          // (BATCH,5)
{
    __shared__ __align__(16) float    xs[S_LEN * MB];                // 16 KB
    __shared__ __align__(16) _Float16 h_buf[2][MB * HSTRIDE];        // 1280 B
    __shared__ __align__(16) float    head_lds[MB * HID + MB * 128]; // c + fc1

    const int tid  = threadIdx.x;
    const int lane = tid & 63;
    const int wave = tid >> 6;        // 0..3
    const int l15  = lane & 15;
    const int quad = lane >> 4;       // 0..3
    const int b0   = blockIdx.x * MB;

    // ---- stage x: 1024 rows of float4 (x[s][b0..b0+3]), 4 rows/thread ----
    {
        float4* xs4 = (float4*)xs;
        #pragma unroll
        for (int t = 0; t < 4; ++t) {
            const int s = tid + 256 * t;
            xs4[s] = *(const float4*)(x + (size_t)s * BATCH + b0);
        }
    }

    // ---- zero both h buffers (h0 = 0) ----
    {
        unsigned* hz = (unsigned*)&h_buf[0][0];
        for (int i = tid; i < 2 * MB * HSTRIDE / 2; i += NTHR) hz[i] = 0u;
    }

    // ---- stationary W_hh B-fragments, per-wave unit slice (32 VGPRs) ----
    // wave w, gate g: frag col n=l15 <-> W_hh row g*64 + 16w + l15.
    // Pre-scaled by -log2e (sigmoid) / -2log2e (tanh on g gate).
    half8 wfrag[4][2];
    #pragma unroll
    for (int g = 0; g < 4; ++g) {
        const float sc = (g == 2) ? (-2.0f * L2E) : (-L2E);
        const float* wr = W_hh + (g * 64 + 16 * wave + l15) * HID + quad * 8;
        #pragma unroll
        for (int kt = 0; kt < 2; ++kt) {
            half8 f;
            #pragma unroll
            for (int j = 0; j < 8; ++j) f[j] = (_Float16)(wr[kt * 32 + j] * sc);
            wfrag[g][kt] = f;
        }
    }

    // ---- elementwise ownership: thread (quad,l15) -> b=quad, u=16*wave+l15 --
    const int u = 16 * wave + l15;
    float wih_s[4], bias_s[4];
    #pragma unroll
    for (int g = 0; g < 4; ++g) {
        const int n = g * 64 + u;
        const float sc = (g == 2) ? (-2.0f * L2E) : (-L2E);
        wih_s[g]  = W_ih[n] * sc;
        bias_s[g] = (b_ih[n] + b_hh[n]) * sc;
    }

    float c = 0.0f;
    const f32x4 zero4 = {0.f, 0.f, 0.f, 0.f};   // persistent C-operand regs

    // hoisted pointers
    const _Float16* a0p = &h_buf[0][0] + (l15 >> 2) * HSTRIDE + quad * 8;
    const _Float16* a1p = &h_buf[1][0] + (l15 >> 2) * HSTRIDE + quad * 8;
    _Float16* w0p = &h_buf[0][0] + quad * HSTRIDE + u;
    _Float16* w1p = &h_buf[1][0] + quad * HSTRIDE + u;
    const float* xp = xs + quad;                 // step s value at xp[4*s]

    __syncthreads();   // x staged + h zeroed visible

    // gate-pre for step 0 (x-projection + bias), maintained one step ahead
    float gpre[4];
    {
        const float xv0 = xp[0];
        #pragma unroll
        for (int g = 0; g < 4; ++g)
            gpre[g] = __builtin_fmaf(xv0, wih_s[g], bias_s[g]);
    }

    auto body = [&](int s, const _Float16* ar, _Float16* hw) {
        // ---- A-frags: replicated rows A[m][k] = h[m>>2][k] ----
        half8 a0 = *(const half8*)(ar);          // k 0..31
        half8 a1 = *(const half8*)(ar + 32);     // k 32..63

        // ---- independent MFMA halves (1-deep dep, not 2-deep chain) ----
        // C[row=quad*4+r][col=l15] = partial gates[batch=quad][unit].
        f32x4 accA[4], accB[4];
        #pragma unroll
        for (int g = 0; g < 4; ++g) {
            accA[g] = __builtin_amdgcn_mfma_f32_16x16x32_f16(a0, wfrag[g][0], zero4, 0, 0, 0);
            accB[g] = __builtin_amdgcn_mfma_f32_16x16x32_f16(a1, wfrag[g][1], zero4, 0, 0, 0);
        }

        // ---- gate assembly: 2 adds, gpre ready since last step ----
        const float gi = (accA[0][0] + accB[0][0]) + gpre[0];
        const float gf = (accA[1][0] + accB[1][0]) + gpre[1];
        const float gg = (accA[2][0] + accB[2][0]) + gpre[2];
        const float go = (accA[3][0] + accB[3][0]) + gpre[3];

        const float eA = __builtin_amdgcn_exp2f(gi);   // e^-ri
        const float eF = __builtin_amdgcn_exp2f(gf);   // e^-rf
        const float eC = __builtin_amdgcn_exp2f(gg);   // e^-2rg
        const float eO = __builtin_amdgcn_exp2f(go);   // e^-ro

        // paired rcp: r = 1/(P*Q) gives f_ = r*Q = 1/P and R1 = r*P = 1/Q
        const float P  = 1.0f + eF;
        const float Q  = (1.0f + eA) * (1.0f + eC);
        const float r  = __builtin_amdgcn_rcpf(P * Q);
        const float f_ = r * Q;
        const float R1 = r * P;
        const float ig = __builtin_fmaf(-eC, R1, R1);  // (1-eC)/Q

        c = __builtin_fmaf(f_, c, ig);

        const float eT = __builtin_amdgcn_exp2f((-2.0f * L2E) * c);
        const float R2 = __builtin_amdgcn_rcpf((1.0f + eO) * (1.0f + eT));
        const float h  = __builtin_fmaf(-eT, R2, R2);

        hw[0] = (_Float16)h;

        // ---- write->barrier shadow: next step's gate-pre ----
        // Last body (s=1023) reads 4B past xs into h_buf (within our LDS
        // allocation): harmless, result unused.
        const float xv = xp[4 * s + 4];
        #pragma unroll
        for (int g = 0; g < 4; ++g)
            gpre[g] = __builtin_fmaf(xv, wih_s[g], bias_s[g]);

        __syncthreads();   // only lgkm pressure: no vm ops in flight
    };

    for (int s = 0; s < S_LEN; s += 2) {
        body(s,     a0p, w1p);   // read h_buf[0], write h_buf[1]
        body(s + 1, a1p, w0p);   // read h_buf[1], write h_buf[0]
    }

    // ---------- fused FC head on final cell state (no activation) ----------
    float* c_lds  = head_lds;            // MB*64 floats: [b][u]
    float* h1_lds = head_lds + MB * HID; // MB*128 floats: [b][j]
    c_lds[quad * HID + u] = c;
    __syncthreads();

    for (int idx = tid; idx < MB * 128; idx += NTHR) {
        const int b = idx >> 7, j = idx & 127;
        const float* wrow = fc1_w + j * HID;
        const float* crow = c_lds + b * HID;
        float acc = fc1_b[j];
        #pragma unroll
        for (int k = 0; k < HID; k += 4)
            acc += crow[k] * wrow[k] + crow[k+1] * wrow[k+1]
                 + crow[k+2] * wrow[k+2] + crow[k+3] * wrow[k+3];
        h1_lds[idx] = acc;
    }
    __syncthreads();

    if (tid < MB * 5) {
        const int b = tid / 5, q = tid % 5;
        const float* wrow = fc2_w + q * 128;
        const float* hrow = h1_lds + b * 128;
        float acc = fc2_b[q];
        #pragma unroll 4
        for (int j = 0; j < 128; ++j) acc += hrow[j] * wrow[j];
        out[(b0 + b) * 5 + q] = acc;
    }
}

extern "C" void kernel_launch(void* const* d_in, const int* in_sizes, int n_in,
                              void* d_out, int out_size, void* d_ws, size_t ws_size,
                              hipStream_t stream) {
    const float* x     = (const float*)d_in[0];
    const float* W_ih  = (const float*)d_in[1];
    const float* W_hh  = (const float*)d_in[2];
    const float* b_ih  = (const float*)d_in[3];
    const float* b_hh  = (const float*)d_in[4];
    const float* fc1_w = (const float*)d_in[5];
    const float* fc1_b = (const float*)d_in[6];
    const float* fc2_w = (const float*)d_in[7];
    const float* fc2_b = (const float*)d_in[8];
    float* out = (float*)d_out;

    lstm_kernel<<<NBLK, NTHR, 0, stream>>>(x, W_ih, W_hh, b_ih, b_hh,
                                           fc1_w, fc1_b, fc2_w, fc2_b, out);
}

// Round 7
// 346.151 us; speedup vs baseline: 2.1285x; 1.0275x over previous
//
#include <hip/hip_runtime.h>
#include <hip/hip_bf16.h>

#define S_LEN 1024
#define BATCH 2048
#define HID   64
#define MB    4               // batch rows per block
#define NBLK  (BATCH / MB)    // 512 blocks -> 2 per CU (measured optimum)
#define NTHR  (MB * HID)      // 256 threads = 4 waves

typedef _Float16 half8 __attribute__((ext_vector_type(8)));
typedef float    f32x4 __attribute__((ext_vector_type(4)));

#define L2E 1.4426950408889634f
#define HSTRIDE 80            // 160 B rows: A-frag b128 reads land 2-way/free

// R18: DESYNC experiment on the exact R2 skeleton (best measured: 313 us).
// Reverts R17's chain edits (4 post-MFMA v_adds cost 10%: the 4 gate chains
// already covered the MFMA dep latency; structure is razor-balanced).
// R2 counter evidence: VALUBusy(54)+MfmaUtil(40)=94% with ~zero overlap ->
// the 2 co-resident blocks phase-lock IN-phase (identical launch+prologue)
// and serialize their pipe phases. R5 forced antiphase with barriers: paid
// 2x barrier cost. Here: ONE-TIME pseudo-random skew (0..~450 cyc, hashed
// from blockIdx) before the loop. Contention dynamics make an offset stable
// (leader's MFMA phase overlaps follower's VALU phase; neither slowed).
// Win signature: VALUBusy+MfmaUtil > 105%, dur ~240-270. Null: flat 313.
// Kept: paired-rcp EW (7 trans, R5/R6-verified numerics, off-path),
// NO setprio (m190), NO C-in fold (R1), NO gpre (R6), 2-deep MFMA (R6).
__global__ __launch_bounds__(NTHR, 2) void lstm_kernel(
    const float* __restrict__ x,      // (S, BATCH)
    const float* __restrict__ W_ih,   // (256,1)
    const float* __restrict__ W_hh,   // (256,64)
    const float* __restrict__ b_ih,   // (256,)
    const float* __restrict__ b_hh,   // (256,)
    const float* __restrict__ fc1_w,  // (128,64)
    const float* __restrict__ fc1_b,  // (128,)
    const float* __restrict__ fc2_w,  // (5,128)
    const float* __restrict__ fc2_b,  // (5,)
    float* __restrict__ out)          // (BATCH,5)
{
    __shared__ __align__(16) float    xs[S_LEN * MB];                // 16 KB
    __shared__ __align__(16) _Float16 h_buf[2][MB * HSTRIDE];        // 1280 B
    __shared__ __align__(16) float    head_lds[MB * HID + MB * 128]; // c + fc1

    const int tid  = threadIdx.x;
    const int lane = tid & 63;
    const int wave = tid >> 6;        // 0..3
    const int l15  = lane & 15;
    const int quad = lane >> 4;       // 0..3
    const int b0   = blockIdx.x * MB;

    // ---- stage x: 1024 rows of float4 (x[s][b0..b0+3]), 4 rows/thread ----
    {
        float4* xs4 = (float4*)xs;
        #pragma unroll
        for (int t = 0; t < 4; ++t) {
            const int s = tid + 256 * t;
            xs4[s] = *(const float4*)(x + (size_t)s * BATCH + b0);
        }
    }

    // ---- zero both h buffers (h0 = 0) ----
    {
        unsigned* hz = (unsigned*)&h_buf[0][0];
        for (int i = tid; i < 2 * MB * HSTRIDE / 2; i += NTHR) hz[i] = 0u;
    }

    // ---- stationary W_hh B-fragments, per-wave unit slice (32 VGPRs) ----
    // wave w, gate g: frag col n=l15 <-> W_hh row g*64 + 16w + l15.
    // B-frag (16x16x32 f16): lane holds B[k=quad*8+j][n=l15]; k-tile kt adds 32.
    // Pre-scaled by -log2e (sigmoid) / -2log2e (tanh on g gate).
    half8 wfrag[4][2];
    #pragma unroll
    for (int g = 0; g < 4; ++g) {
        const float sc = (g == 2) ? (-2.0f * L2E) : (-L2E);
        const float* wr = W_hh + (g * 64 + 16 * wave + l15) * HID + quad * 8;
        #pragma unroll
        for (int kt = 0; kt < 2; ++kt) {
            half8 f;
            #pragma unroll
            for (int j = 0; j < 8; ++j) f[j] = (_Float16)(wr[kt * 32 + j] * sc);
            wfrag[g][kt] = f;
        }
    }

    // ---- elementwise ownership: thread (quad,l15) -> b=quad, u=16*wave+l15 --
    const int u = 16 * wave + l15;
    float wih_s[4], bias_s[4];
    #pragma unroll
    for (int g = 0; g < 4; ++g) {
        const int n = g * 64 + u;
        const float sc = (g == 2) ? (-2.0f * L2E) : (-L2E);
        wih_s[g]  = W_ih[n] * sc;
        bias_s[g] = (b_ih[n] + b_hh[n]) * sc;
    }

    float c = 0.0f;
    const f32x4 zero4 = {0.f, 0.f, 0.f, 0.f};   // persistent C-operand regs

    // hoisted pointers
    const _Float16* a0p = &h_buf[0][0] + (l15 >> 2) * HSTRIDE + quad * 8;
    const _Float16* a1p = &h_buf[1][0] + (l15 >> 2) * HSTRIDE + quad * 8;
    _Float16* w0p = &h_buf[0][0] + quad * HSTRIDE + u;
    _Float16* w1p = &h_buf[1][0] + quad * HSTRIDE + u;
    const float* xp = xs + quad;                 // step s value at xp[4*s]

    __syncthreads();   // x staged + h zeroed visible

    // ---- one-time pseudo-random phase skew (R18 experiment) ----
    // iters in 0..15 from a Knuth-hash of blockIdx: co-resident blocks get
    // distinct skews with P=15/16 regardless of the (undocumented) block->CU
    // pairing. Each iter is a dependent rcp+add (~20-30 cyc): max ~450 cyc,
    // about half a recurrence step. Dead-store guard keeps the chain live.
    {
        const unsigned it = ((unsigned)blockIdx.x * 2654435761u) >> 28;
        float d = (float)(lane + 2);
        #pragma unroll 1
        for (unsigned i = 0; i < it; ++i)
            d = __builtin_amdgcn_rcpf(d) + 1.0f;
        if (d == 1234.5678f) head_lds[0] = d;   // never true
    }

    auto body = [&](int s, const _Float16* ar, _Float16* hw) {
        const float xv = xp[4 * s];              // ds broadcast (16 lanes/addr)

        // ---- MFMA with replicated A: A[m][k] = h[m>>2][k] ----
        // C[row=quad*4+r][col=l15] = gates[batch=quad][unit], identical over r.
        half8 a0 = *(const half8*)(ar);          // k 0..31
        half8 a1 = *(const half8*)(ar + 32);     // k 32..63

        f32x4 acc[4];
        #pragma unroll
        for (int g = 0; g < 4; ++g) {
            acc[g] = __builtin_amdgcn_mfma_f32_16x16x32_f16(a0, wfrag[g][0], zero4, 0, 0, 0);
            acc[g] = __builtin_amdgcn_mfma_f32_16x16x32_f16(a1, wfrag[g][1], acc[g], 0, 0, 0);
        }

        // ---- elementwise: gates register-resident in acc[g][0] ----
        const float gi = acc[0][0] + __builtin_fmaf(xv, wih_s[0], bias_s[0]);
        const float gf = acc[1][0] + __builtin_fmaf(xv, wih_s[1], bias_s[1]);
        const float gg = acc[2][0] + __builtin_fmaf(xv, wih_s[2], bias_s[2]);
        const float go = acc[3][0] + __builtin_fmaf(xv, wih_s[3], bias_s[3]);

        const float eA = __builtin_amdgcn_exp2f(gi);   // e^-ri
        const float eF = __builtin_amdgcn_exp2f(gf);   // e^-rf
        const float eC = __builtin_amdgcn_exp2f(gg);   // e^-2rg
        const float eO = __builtin_amdgcn_exp2f(go);   // e^-ro

        // paired rcp: r = 1/(P*Q) gives f_ = r*Q = 1/P and R1 = r*P = 1/Q
        const float P  = 1.0f + eF;
        const float Q  = (1.0f + eA) * (1.0f + eC);
        const float r  = __builtin_amdgcn_rcpf(P * Q);
        const float f_ = r * Q;
        const float R1 = r * P;
        const float ig = __builtin_fmaf(-eC, R1, R1);  // (1-eC)/Q

        c = __builtin_fmaf(f_, c, ig);

        const float eT = __builtin_amdgcn_exp2f((-2.0f * L2E) * c);
        const float R2 = __builtin_amdgcn_rcpf((1.0f + eO) * (1.0f + eT));
        const float h  = __builtin_fmaf(-eT, R2, R2);

        hw[0] = (_Float16)h;
        __syncthreads();   // only lgkm pressure: no vm ops in flight
    };

    for (int s = 0; s < S_LEN; s += 2) {
        body(s,     a0p, w1p);   // read h_buf[0], write h_buf[1]
        body(s + 1, a1p, w0p);   // read h_buf[1], write h_buf[0]
    }

    // ---------- fused FC head on final cell state (no activation) ----------
    float* c_lds  = head_lds;            // MB*64 floats: [b][u]
    float* h1_lds = head_lds + MB * HID; // MB*128 floats: [b][j]
    c_lds[quad * HID + u] = c;
    __syncthreads();

    for (int idx = tid; idx < MB * 128; idx += NTHR) {
        const int b = idx >> 7, j = idx & 127;
        const float* wrow = fc1_w + j * HID;
        const float* crow = c_lds + b * HID;
        float acc = fc1_b[j];
        #pragma unroll
        for (int k = 0; k < HID; k += 4)
            acc += crow[k] * wrow[k] + crow[k+1] * wrow[k+1]
                 + crow[k+2] * wrow[k+2] + crow[k+3] * wrow[k+3];
        h1_lds[idx] = acc;
    }
    __syncthreads();

    if (tid < MB * 5) {
        const int b = tid / 5, q = tid % 5;
        const float* wrow = fc2_w + q * 128;
        const float* hrow = h1_lds + b * 128;
        float acc = fc2_b[q];
        #pragma unroll 4
        for (int j = 0; j < 128; ++j) acc += hrow[j] * wrow[j];
        out[(b0 + b) * 5 + q] = acc;
    }
}

extern "C" void kernel_launch(void* const* d_in, const int* in_sizes, int n_in,
                              void* d_out, int out_size, void* d_ws, size_t ws_size,
                              hipStream_t stream) {
    const float* x     = (const float*)d_in[0];
    const float* W_ih  = (const float*)d_in[1];
    const float* W_hh  = (const float*)d_in[2];
    const float* b_ih  = (const float*)d_in[3];
    const float* b_hh  = (const float*)d_in[4];
    const float* fc1_w = (const float*)d_in[5];
    const float* fc1_b = (const float*)d_in[6];
    const float* fc2_w = (const float*)d_in[7];
    const float* fc2_b = (const float*)d_in[8];
    float* out = (float*)d_out;

    lstm_kernel<<<NBLK, NTHR, 0, stream>>>(x, W_ih, W_hh, b_ih, b_hh,
                                           fc1_w, fc1_b, fc2_w, fc2_b, out);
}

// Round 8
// 331.134 us; speedup vs baseline: 2.2250x; 1.0454x over previous
//
#include <hip/hip_runtime.h>
#include <hip/hip_bf16.h>

#define S_LEN 1024
#define BATCH 2048
#define HID   64
#define MB    4               // batch rows per block
#define NBLK  (BATCH / MB)    // 512 blocks -> 2 per CU (measured optimum)
#define NTHR  (MB * HID)      // 256 threads = 4 waves

typedef _Float16 half8 __attribute__((ext_vector_type(8)));
typedef float    f32x4 __attribute__((ext_vector_type(4)));

#define L2E 1.4426950408889634f
#define HSTRIDE 80            // 160 B rows: A-frag b128 reads land 2-way/free

// FINAL (R19): exact restoration of the session-best kernel (313 us, x3).
// Structural map (R13-R18): issue reduction null (latency-bound, not
// issue-bound); merged-block ILP 407; barrier-free wave-per-row 777 (MFMA
// is 19.4 cyc/SIMD -> replication kills); antiphase 503 (barriers dominate);
// on-path chain edits 344 (+~7us per dependent op on the c/h chain);
// desync+paired-rcp 324 (phase-lock not the mechanism; paired-rcp put 2 ops
// on the c chain). Floor analysis: 1024 serial steps x ~735 cyc
// barrier-to-barrier chain (ds_read ~130 + MFMA ~100 + EW trans ~150 +
// write/barrier ~100, braided ~53% across the 2 co-resident blocks).
// HBM 1.4%, conflicts negligible. Grid arithmetic (BATCH=2048, 256 CU)
// blocks every replication-reducing tiling without dropping to 1 blk/CU.
// Invariants: NO setprio (m190 lockstep null), NO f32x4 C-in fold (R1:
// +13% VALU rematerialization), NO paired-rcp on the f_ path (R7),
// NO post-MFMA adds (R6), separate rcp per gate pair as below.
__global__ __launch_bounds__(NTHR, 2) void lstm_kernel(
    const float* __restrict__ x,      // (S, BATCH)
    const float* __restrict__ W_ih,   // (256,1)
    const float* __restrict__ W_hh,   // (256,64)
    const float* __restrict__ b_ih,   // (256,)
    const float* __restrict__ b_hh,   // (256,)
    const float* __restrict__ fc1_w,  // (128,64)
    const float* __restrict__ fc1_b,  // (128,)
    const float* __restrict__ fc2_w,  // (5,128)
    const float* __restrict__ fc2_b,  // (5,)
    float* __restrict__ out)          // (BATCH,5)
{
    // x slice staged ONCE (16 KB): no global loads in the recurrence loop ->
    // the barrier's implicit vmcnt(0) drain is free.
    __shared__ __align__(16) float    xs[S_LEN * MB];                // 16 KB
    __shared__ __align__(16) _Float16 h_buf[2][MB * HSTRIDE];        // 1280 B
    __shared__ __align__(16) float    head_lds[MB * HID + MB * 128]; // c + fc1

    const int tid  = threadIdx.x;
    const int lane = tid & 63;
    const int wave = tid >> 6;        // 0..3
    const int l15  = lane & 15;
    const int quad = lane >> 4;       // 0..3
    const int b0   = blockIdx.x * MB;

    // ---- stage x: 1024 rows of float4 (x[s][b0..b0+3]), 4 rows/thread ----
    {
        float4* xs4 = (float4*)xs;
        #pragma unroll
        for (int t = 0; t < 4; ++t) {
            const int s = tid + 256 * t;
            xs4[s] = *(const float4*)(x + (size_t)s * BATCH + b0);
        }
    }

    // ---- zero both h buffers (h0 = 0) ----
    {
        unsigned* hz = (unsigned*)&h_buf[0][0];
        for (int i = tid; i < 2 * MB * HSTRIDE / 2; i += NTHR) hz[i] = 0u;
    }

    // ---- stationary W_hh B-fragments, per-wave unit slice (32 VGPRs) ----
    // wave w, gate g: frag col n=l15 <-> W_hh row g*64 + 16w + l15.
    // B-frag (16x16x32 f16): lane holds B[k=quad*8+j][n=l15]; k-tile kt adds 32.
    // Pre-scaled by -log2e (sigmoid) / -2log2e (tanh on g gate).
    half8 wfrag[4][2];
    #pragma unroll
    for (int g = 0; g < 4; ++g) {
        const float sc = (g == 2) ? (-2.0f * L2E) : (-L2E);
        const float* wr = W_hh + (g * 64 + 16 * wave + l15) * HID + quad * 8;
        #pragma unroll
        for (int kt = 0; kt < 2; ++kt) {
            half8 f;
            #pragma unroll
            for (int j = 0; j < 8; ++j) f[j] = (_Float16)(wr[kt * 32 + j] * sc);
            wfrag[g][kt] = f;
        }
    }

    // ---- elementwise ownership: thread (quad,l15) -> b=quad, u=16*wave+l15 --
    const int u = 16 * wave + l15;
    float wih_s[4], bias_s[4];
    #pragma unroll
    for (int g = 0; g < 4; ++g) {
        const int n = g * 64 + u;
        const float sc = (g == 2) ? (-2.0f * L2E) : (-L2E);
        wih_s[g]  = W_ih[n] * sc;
        bias_s[g] = (b_ih[n] + b_hh[n]) * sc;
    }

    float c = 0.0f;
    const f32x4 zero4 = {0.f, 0.f, 0.f, 0.f};   // persistent C-operand regs

    // hoisted pointers
    const _Float16* a0p = &h_buf[0][0] + (l15 >> 2) * HSTRIDE + quad * 8;
    const _Float16* a1p = &h_buf[1][0] + (l15 >> 2) * HSTRIDE + quad * 8;
    _Float16* w0p = &h_buf[0][0] + quad * HSTRIDE + u;
    _Float16* w1p = &h_buf[1][0] + quad * HSTRIDE + u;
    const float* xp = xs + quad;                 // step s value at xp[4*s]

    __syncthreads();   // x staged + h zeroed visible

    auto body = [&](int s, const _Float16* ar, _Float16* hw) {
        const float xv = xp[4 * s];              // ds broadcast (16 lanes/addr)

        // ---- MFMA with replicated A: A[m][k] = h[m>>2][k] ----
        // C[row=quad*4+r][col=l15] = gates[batch=quad][unit], identical over r.
        half8 a0 = *(const half8*)(ar);          // k 0..31
        half8 a1 = *(const half8*)(ar + 32);     // k 32..63

        f32x4 acc[4];
        #pragma unroll
        for (int g = 0; g < 4; ++g) {
            acc[g] = __builtin_amdgcn_mfma_f32_16x16x32_f16(a0, wfrag[g][0], zero4, 0, 0, 0);
            acc[g] = __builtin_amdgcn_mfma_f32_16x16x32_f16(a1, wfrag[g][1], acc[g], 0, 0, 0);
        }

        // ---- elementwise: gates register-resident in acc[g][0] ----
        // All pre-scaled: gi = -L2E*ri, gf = -L2E*rf, gg = -2L2E*rg, go = -L2E*ro
        const float gi = acc[0][0] + __builtin_fmaf(xv, wih_s[0], bias_s[0]);
        const float gf = acc[1][0] + __builtin_fmaf(xv, wih_s[1], bias_s[1]);
        const float gg = acc[2][0] + __builtin_fmaf(xv, wih_s[2], bias_s[2]);
        const float go = acc[3][0] + __builtin_fmaf(xv, wih_s[3], bias_s[3]);

        const float eA = __builtin_amdgcn_exp2f(gi);   // e^-ri
        const float eF = __builtin_amdgcn_exp2f(gf);   // e^-rf
        const float eC = __builtin_amdgcn_exp2f(gg);   // e^-2rg
        const float eO = __builtin_amdgcn_exp2f(go);   // e^-ro

        // rcp fusion: sigma(ri)*tanh(rg) = (1-eC) / ((1+eA)(1+eC))
        //             sigma(ro)*tanh(c)  = (1-eT) / ((1+eO)(1+eT))
        // f_ keeps its own rcp: shortest possible c-critical-chain (R7 lesson).
        const float f_ = __builtin_amdgcn_rcpf(1.0f + eF);
        const float R1 = __builtin_amdgcn_rcpf((1.0f + eA) * (1.0f + eC));
        const float ig = __builtin_fmaf(-eC, R1, R1);

        c = __builtin_fmaf(f_, c, ig);

        const float eT = __builtin_amdgcn_exp2f((-2.0f * L2E) * c);
        const float R2 = __builtin_amdgcn_rcpf((1.0f + eO) * (1.0f + eT));
        const float h  = __builtin_fmaf(-eT, R2, R2);

        hw[0] = (_Float16)h;
        __syncthreads();   // only lgkm pressure: no vm ops in flight
    };

    for (int s = 0; s < S_LEN; s += 2) {
        body(s,     a0p, w1p);   // read h_buf[0], write h_buf[1]
        body(s + 1, a1p, w0p);   // read h_buf[1], write h_buf[0]
    }

    // ---------- fused FC head on final cell state (no activation) ----------
    float* c_lds  = head_lds;            // MB*64 floats: [b][u]
    float* h1_lds = head_lds + MB * HID; // MB*128 floats: [b][j]
    c_lds[quad * HID + u] = c;
    __syncthreads();

    for (int idx = tid; idx < MB * 128; idx += NTHR) {
        const int b = idx >> 7, j = idx & 127;
        const float* wrow = fc1_w + j * HID;
        const float* crow = c_lds + b * HID;
        float acc = fc1_b[j];
        #pragma unroll
        for (int k = 0; k < HID; k += 4)
            acc += crow[k] * wrow[k] + crow[k+1] * wrow[k+1]
                 + crow[k+2] * wrow[k+2] + crow[k+3] * wrow[k+3];
        h1_lds[idx] = acc;
    }
    __syncthreads();

    if (tid < MB * 5) {
        const int b = tid / 5, q = tid % 5;
        const float* wrow = fc2_w + q * 128;
        const float* hrow = h1_lds + b * 128;
        float acc = fc2_b[q];
        #pragma unroll 4
        for (int j = 0; j < 128; ++j) acc += hrow[j] * wrow[j];
        out[(b0 + b) * 5 + q] = acc;
    }
}

extern "C" void kernel_launch(void* const* d_in, const int* in_sizes, int n_in,
                              void* d_out, int out_size, void* d_ws, size_t ws_size,
                              hipStream_t stream) {
    const float* x     = (const float*)d_in[0];
    const float* W_ih  = (const float*)d_in[1];
    const float* W_hh  = (const float*)d_in[2];
    const float* b_ih  = (const float*)d_in[3];
    const float* b_hh  = (const float*)d_in[4];
    const float* fc1_w = (const float*)d_in[5];
    const float* fc1_b = (const float*)d_in[6];
    const float* fc2_w = (const float*)d_in[7];
    const float* fc2_b = (const float*)d_in[8];
    float* out = (float*)d_out;

    lstm_kernel<<<NBLK, NTHR, 0, stream>>>(x, W_ih, W_hh, b_ih, b_hh,
                                           fc1_w, fc1_b, fc2_w, fc2_b, out);
}